// Round 6
// baseline (357.517 us; speedup 1.0000x reference)
//
#include <hip/hip_runtime.h>
#include <hip/hip_fp16.h>
#include <math.h>

#define LOG2E 1.4426950408889634f
#define LN2F  0.6931471805599453f

constexpr int M   = 2048;
constexpr int N   = 2048;
constexpr int D   = 256;
constexpr int K   = 2048;   // reduce length (both directions)
constexpr int MP1 = 2049;   // M+1 == N+1
constexpr int UVS = 2052;   // padded u/v batch stride -> float4-aligned rows

struct alignas(16) half8 { __half2 h[4]; };

__device__ inline half8 pack_half8(const float4& a, const float4& b) {
    half8 r;
    r.h[0] = __floats2half2_rn(a.x, a.y);
    r.h[1] = __floats2half2_rn(a.z, a.w);
    r.h[2] = __floats2half2_rn(b.x, b.y);
    r.h[3] = __floats2half2_rn(b.z, b.w);
    return r;
}

__device__ inline float fast_exp2(float x) {
#if __has_builtin(__builtin_amdgcn_exp2f)
    return __builtin_amdgcn_exp2f(x);
#else
    return exp2f(x);
#endif
}
__device__ inline float fast_log2(float x) {
#if __has_builtin(__builtin_amdgcn_logf)
    return __builtin_amdgcn_logf(x);   // v_log_f32 is log2
#else
    return log2f(x);
#endif
}
// NaN-guarded exp2 for identity (-inf) merges
__device__ inline float exp2g(float x) { return fast_exp2(fmaxf(x, -20000.0f)); }

__device__ inline void insert5(float t[5], float y) {
    float v = y, mx;
    #pragma unroll
    for (int k = 0; k < 5; ++k) { mx = fmaxf(t[k], v); v = fminf(t[k], v); t[k] = mx; }
}

__device__ inline void ce_desc(float& a, float& b) {
    float hi = fmaxf(a, b), lo = fminf(a, b); a = hi; b = lo;
}
// 19-CE sorting network for 8 elements, descending (y[0] = max).
__device__ inline void sort8_desc(float y[8]) {
    ce_desc(y[0],y[1]); ce_desc(y[2],y[3]); ce_desc(y[4],y[5]); ce_desc(y[6],y[7]);
    ce_desc(y[0],y[2]); ce_desc(y[1],y[3]); ce_desc(y[4],y[6]); ce_desc(y[5],y[7]);
    ce_desc(y[1],y[2]); ce_desc(y[5],y[6]); ce_desc(y[0],y[4]); ce_desc(y[3],y[7]);
    ce_desc(y[1],y[5]); ce_desc(y[2],y[6]);
    ce_desc(y[1],y[4]); ce_desc(y[3],y[6]);
    ce_desc(y[2],y[4]); ce_desc(y[3],y[5]);
    ce_desc(y[3],y[4]);
}

// merge sorted-desc top5 lists + lse states (full version, used by legacy paths)
__device__ inline void merge5(float a[5], float& as, const float b[5], float bs) {
    float r0 = fmaxf(a[0], b[0]);
    float r1 = fmaxf(fmaxf(a[1], b[1]), fminf(a[0], b[0]));
    float r2 = fmaxf(fmaxf(a[2], b[2]), fmaxf(fminf(a[1], b[0]), fminf(a[0], b[1])));
    float r3 = fmaxf(fmaxf(a[3], b[3]),
               fmaxf(fmaxf(fminf(a[2], b[0]), fminf(a[1], b[1])), fminf(a[0], b[2])));
    float r4 = fmaxf(fmaxf(a[4], b[4]),
               fmaxf(fmaxf(fminf(a[3], b[0]), fminf(a[2], b[1])),
                     fmaxf(fminf(a[1], b[2]), fminf(a[0], b[3]))));
    as = as * exp2g(a[0] - r0) + bs * exp2g(b[0] - r0);
    a[0] = r0; a[1] = r1; a[2] = r2; a[3] = r3; a[4] = r4;
}

// top5-only merge: no lse state, no exp2 -- pure min/max network
__device__ inline void merge5t(float a[5], const float b[5]) {
    float r0 = fmaxf(a[0], b[0]);
    float r1 = fmaxf(fmaxf(a[1], b[1]), fminf(a[0], b[0]));
    float r2 = fmaxf(fmaxf(a[2], b[2]), fmaxf(fminf(a[1], b[0]), fminf(a[0], b[1])));
    float r3 = fmaxf(fmaxf(a[3], b[3]),
               fmaxf(fmaxf(fminf(a[2], b[0]), fminf(a[1], b[1])), fminf(a[0], b[2])));
    float r4 = fmaxf(fmaxf(a[4], b[4]),
               fmaxf(fmaxf(fminf(a[3], b[0]), fminf(a[2], b[1])),
                     fmaxf(fminf(a[1], b[2]), fminf(a[0], b[3]))));
    a[0] = r0; a[1] = r1; a[2] = r2; a[3] = r3; a[4] = r4;
}

__device__ inline void merge5t_shfl_xor(float t[5], int off) {
    float b[5];
    #pragma unroll
    for (int k = 0; k < 5; ++k) b[k] = __shfl_xor(t[k], off, 64);
    merge5t(t, b);
}

__device__ inline void merge5_shfl_xor(float t[5], float& s, int off) {
    float b[5], bs;
    #pragma unroll
    for (int k = 0; k < 5; ++k) b[k] = __shfl_xor(t[k], off, 64);
    bs = __shfl_xor(s, off, 64);
    merge5(t, s, b, bs);
}

// dual butterfly level: two independent states interleaved (row0 uses this)
__device__ inline void merge5_shfl_xor2(float tA[5], float& sA, float tB[5], float& sB, int off) {
    float bA[5], bB[5];
    #pragma unroll
    for (int k = 0; k < 5; ++k) { bA[k] = __shfl_xor(tA[k], off, 64); bB[k] = __shfl_xor(tB[k], off, 64); }
    float bsA = __shfl_xor(sA, off, 64);
    float bsB = __shfl_xor(sB, off, 64);
    merge5(tA, sA, bA, bsA);
    merge5(tB, sB, bB, bsB);
}

__device__ inline void online_add(float t[5], float& s, float y) {
    float m_old = t[0];
    float m_new = fmaxf(m_old, y);
    s = s * exp2g(m_old - m_new) + fast_exp2(y - m_new);
    insert5(t, y);
}

// legacy: sort group of 8, fold into (t,s) accumulator (row0 uses this)
__device__ inline void group_accum(bool first, float t[5], float& s, float z[8]) {
    sort8_desc(z);
    float gs = 1.0f;
    #pragma unroll
    for (int k = 1; k < 8; ++k) gs += fast_exp2(z[k] - z[0]);
    if (first) { t[0]=z[0]; t[1]=z[1]; t[2]=z[2]; t[3]=z[3]; t[4]=z[4]; s = gs; }
    else merge5(t, s, z, gs);
}

// new: sort group of 8, record per-group (max, sum-at-max), fold top5 only
__device__ inline void group_accum_t(bool first, float t[5], float z[8],
                                     float& mgv, float& sgv) {
    sort8_desc(z);
    float gs = 1.0f;
    #pragma unroll
    for (int k = 1; k < 8; ++k) gs += fast_exp2(z[k] - z[0]);
    mgv = z[0]; sgv = gs;
    if (first) { t[0]=z[0]; t[1]=z[1]; t[2]=z[2]; t[3]=z[3]; t[4]=z[4]; }
    else merge5t(t, z);
}

__device__ inline float gelu_exact(float x) {
    return 0.5f * x * (1.0f + erff(x * 0.70710678118654752f));
}

__device__ inline float wave_sum(float x) {
    #pragma unroll
    for (int off = 32; off >= 1; off >>= 1) x += __shfl_xor(x, off, 64);
    return x;
}
__device__ inline void wave_sum2(float& x, float& y) {
    #pragma unroll
    for (int off = 32; off >= 1; off >>= 1) {
        float xs = __shfl_xor(x, off, 64);
        float ys = __shfl_xor(y, off, 64);
        x += xs; y += ys;
    }
}

// one-wave MLP, fast LN (single wave_sum2 of (sum, sumsq) per LN).
__device__ inline float mlp_wave_fast(const float f[16], int j,
    const float* __restrict__ w1, const float* __restrict__ b1,
    const float* __restrict__ g1, const float* __restrict__ be1,
    const float* __restrict__ w2, const float* __restrict__ b2,
    const float* __restrict__ g2, const float* __restrict__ be2,
    const float* __restrict__ w3, const float* __restrict__ b3)
{
    float h = b1[j];
    #pragma unroll
    for (int k = 0; k < 16; ++k) h = fmaf(f[k], w1[j * 16 + k], h);
    h = gelu_exact(h);
    float sm = h, sq = h * h;
    wave_sum2(sm, sq);
    float mu  = sm * (1.0f / 64.0f);
    float var = sq * (1.0f / 64.0f) - mu * mu;
    float hn  = (h - mu) * rsqrtf(var + 1e-5f) * g1[j] + be1[j];

    float a0 = b2[j], a1 = 0.0f;
    #pragma unroll
    for (int k = 0; k < 64; k += 2) {
        a0 = fmaf(__shfl(hn, k, 64),     w2[j * 64 + k],     a0);
        a1 = fmaf(__shfl(hn, k + 1, 64), w2[j * 64 + k + 1], a1);
    }
    float h2 = gelu_exact(a0 + a1);
    sm = h2; sq = h2 * h2;
    wave_sum2(sm, sq);
    mu  = sm * (1.0f / 64.0f);
    var = sq * (1.0f / 64.0f) - mu * mu;
    float hn2 = (h2 - mu) * rsqrtf(var + 1e-5f) * g2[j] + be2[j];
    return wave_sum(hn2 * w3[j]) + b3[0];
}

// one-wave MLP (exact LN, row0 legacy)
__device__ inline float mlp_wave(const float f[16], int j,
    const float* __restrict__ w1, const float* __restrict__ b1,
    const float* __restrict__ g1, const float* __restrict__ be1,
    const float* __restrict__ w2, const float* __restrict__ b2,
    const float* __restrict__ g2, const float* __restrict__ be2,
    const float* __restrict__ w3, const float* __restrict__ b3)
{
    float h = b1[j];
    #pragma unroll
    for (int k = 0; k < 16; ++k) h = fmaf(f[k], w1[j * 16 + k], h);
    h = gelu_exact(h);
    float mu  = wave_sum(h) * (1.0f / 64.0f);
    float d   = h - mu;
    float var = wave_sum(d * d) * (1.0f / 64.0f);
    float hn  = d * rsqrtf(var + 1e-5f) * g1[j] + be1[j];
    float h2 = b2[j];
    #pragma unroll
    for (int k = 0; k < 64; ++k) h2 = fmaf(__shfl(hn, k, 64), w2[j * 64 + k], h2);
    h2 = gelu_exact(h2);
    mu  = wave_sum(h2) * (1.0f / 64.0f);
    d   = h2 - mu;
    var = wave_sum(d * d) * (1.0f / 64.0f);
    float hn2 = d * rsqrtf(var + 1e-5f) * g2[j] + be2[j];
    return wave_sum(hn2 * w3[j]) + b3[0];
}

// dual MLP (row0 uses this)
__device__ inline void mlp_wave2(const float fA[16], const float fB[16], int j,
    const float* __restrict__ w1, const float* __restrict__ b1,
    const float* __restrict__ g1, const float* __restrict__ be1,
    const float* __restrict__ w2, const float* __restrict__ b2,
    const float* __restrict__ g2, const float* __restrict__ be2,
    const float* __restrict__ w3, const float* __restrict__ b3,
    float& oA, float& oB)
{
    float hA = b1[j], hB = hA;
    #pragma unroll
    for (int k = 0; k < 16; ++k) {
        float w = w1[j * 16 + k];
        hA = fmaf(fA[k], w, hA);
        hB = fmaf(fB[k], w, hB);
    }
    hA = gelu_exact(hA); hB = gelu_exact(hB);
    float muA = hA, muB = hB;
    wave_sum2(muA, muB);
    muA *= (1.0f / 64.0f); muB *= (1.0f / 64.0f);
    float dA = hA - muA, dB = hB - muB;
    float vA = dA * dA, vB = dB * dB;
    wave_sum2(vA, vB);
    vA *= (1.0f / 64.0f); vB *= (1.0f / 64.0f);
    float hnA = dA * rsqrtf(vA + 1e-5f) * g1[j] + be1[j];
    float hnB = dB * rsqrtf(vB + 1e-5f) * g1[j] + be1[j];

    float a0A = b2[j], a1A = 0.0f, a0B = b2[j], a1B = 0.0f;
    #pragma unroll
    for (int k = 0; k < 64; k += 2) {
        float w0 = w2[j * 64 + k], w1v = w2[j * 64 + k + 1];
        float sA0 = __shfl(hnA, k, 64),     sB0 = __shfl(hnB, k, 64);
        float sA1 = __shfl(hnA, k + 1, 64), sB1 = __shfl(hnB, k + 1, 64);
        a0A = fmaf(sA0, w0, a0A); a0B = fmaf(sB0, w0, a0B);
        a1A = fmaf(sA1, w1v, a1A); a1B = fmaf(sB1, w1v, a1B);
    }
    float h2A = gelu_exact(a0A + a1A), h2B = gelu_exact(a0B + a1B);
    muA = h2A; muB = h2B;
    wave_sum2(muA, muB);
    muA *= (1.0f / 64.0f); muB *= (1.0f / 64.0f);
    dA = h2A - muA; dB = h2B - muB;
    vA = dA * dA; vB = dB * dB;
    wave_sum2(vA, vB);
    vA *= (1.0f / 64.0f); vB *= (1.0f / 64.0f);
    float hn2A = dA * rsqrtf(vA + 1e-5f) * g2[j] + be2[j];
    float hn2B = dB * rsqrtf(vB + 1e-5f) * g2[j] + be2[j];
    float zA = hn2A * w3[j], zB = hn2B * w3[j];
    wave_sum2(zA, zB);
    oA = zA + b3[0];
    oB = zB + b3[0];
}

__device__ inline void feats_from(const float t[5], float s, float l2w,
                                  const float* __restrict__ dd, float f[16], float& un)
{
    float lse = t[0] + fast_log2(s);
    un = l2w - lse;
    f[0] = l2w * LN2F;
    f[1] = un  * LN2F;
    f[2] = 0.0f;
    f[3] = (t[0] - t[1]) * LN2F;
    f[4] = (t[0] - t[2]) * LN2F;
    f[5] = (t[0] - t[3]) * LN2F;
    f[6] = (t[0] - t[4]) * LN2F;
    f[7] = (lse - t[0]) * LN2F;
    #pragma unroll
    for (int p = 0; p < 8; ++p) f[8 + p] = dd[p];
}

// ---------------------------------------------------------------------------
// proj, K-split: grid (9, B, 16) [z = which*8 + ks], block 256.
// ---------------------------------------------------------------------------
__global__ __launch_bounds__(256) void proj_part(
    const float* __restrict__ mdesc0, const float* __restrict__ mdesc1,
    const float* __restrict__ pA_w, const float* __restrict__ pB_w,
    float* __restrict__ ppart, int B)
{
    const int which = blockIdx.z >> 3;
    const int ks    = blockIdx.z & 7;
    const float* mdesc = which ? mdesc1 : mdesc0;
    const float* pw    = which ? pB_w : pA_w;

    __shared__ float swT[32 * 8];   // swT[d0*8+p]
    const int tid = threadIdx.x;
    {
        int p = tid >> 5, d0 = tid & 31;
        swT[d0 * 8 + p] = pw[p * D + ks * 32 + d0];
    }
    __syncthreads();

    const int m = blockIdx.x * 256 + tid;
    const int b = blockIdx.y;
    if (m >= M) return;

    float acc[8];
    #pragma unroll
    for (int p = 0; p < 8; ++p) acc[p] = 0.0f;
    const float* base = mdesc + ((size_t)b * D + ks * 32) * M + m;
    #pragma unroll 4
    for (int d0 = 0; d0 < 32; ++d0) {
        float x = base[(size_t)d0 * M];
        #pragma unroll
        for (int p = 0; p < 8; ++p) acc[p] = fmaf(x, swT[d0 * 8 + p], acc[p]);
    }
    float4* o = (float4*)(ppart + (((size_t)(which * B + b)) * MP1 + m) * 64 + ks * 8);
    o[0] = make_float4(acc[0], acc[1], acc[2], acc[3]);
    o[1] = make_float4(acc[4], acc[5], acc[6], acc[7]);
}

// grid (9, B, 2), block 256: sum 8 K-partials + bias; dustbin row m==M -> 0
__global__ __launch_bounds__(256) void proj_combine(
    const float* __restrict__ ppart,
    const float* __restrict__ pA_b, const float* __restrict__ pB_b,
    float* __restrict__ dA, float* __restrict__ dB, int B)
{
    const int which = blockIdx.z;
    const float* pb = which ? pB_b : pA_b;
    float* dOut     = which ? dB   : dA;
    const int m = blockIdx.x * 256 + threadIdx.x;
    const int b = blockIdx.y;
    if (m > M) return;
    float* out = dOut + ((size_t)b * MP1 + m) * 8;
    if (m == M) {
        #pragma unroll
        for (int p = 0; p < 8; ++p) out[p] = 0.0f;
        return;
    }
    float acc[8];
    #pragma unroll
    for (int p = 0; p < 8; ++p) acc[p] = pb[p];
    const float4* pp = (const float4*)(ppart + (((size_t)(which * B + b)) * MP1 + m) * 64);
    #pragma unroll
    for (int ks = 0; ks < 8; ++ks) {
        float4 x0 = pp[2 * ks], x1 = pp[2 * ks + 1];
        acc[0] += x0.x; acc[1] += x0.y; acc[2] += x0.z; acc[3] += x0.w;
        acc[4] += x1.x; acc[5] += x1.y; acc[6] += x1.z; acc[7] += x1.w;
    }
    #pragma unroll
    for (int p = 0; p < 8; ++p) out[p] = acc[p];
}

// ---------------------------------------------------------------------------
// Iter-0 row pass: reads fp32 scores (v==0), writes fp16 copy sh, fused MLP.
// grid (257, B), block 256 = 4 waves, TWO rows per wave. (unchanged)
// ---------------------------------------------------------------------------
__global__ __launch_bounds__(256) void row0_fused(
    const float* __restrict__ scores, __half* __restrict__ sh,
    const float* __restrict__ alpha, const float* __restrict__ dA,
    float* __restrict__ u,
    const float* __restrict__ w1, const float* __restrict__ b1,
    const float* __restrict__ g1, const float* __restrict__ be1,
    const float* __restrict__ w2, const float* __restrict__ b2,
    const float* __restrict__ g2, const float* __restrict__ be2,
    const float* __restrict__ w3, const float* __restrict__ b3)
{
    const int tid  = threadIdx.x;
    const int lane = tid & 63;
    const int wv   = tid >> 6;
    const int pair = blockIdx.x * 4 + wv;
    const int r0   = pair * 2;
    if (r0 >= MP1) return;
    const int b = blockIdx.y;
    const float alpha2 = alpha[0] * LOG2E;

    if (r0 < M) {
        const float4* sA4 = (const float4*)(scores + ((size_t)b * M + r0) * N);
        const float4* sB4 = sA4 + (N / 4);
        half8* hA8 = (half8*)(sh + ((size_t)b * M + r0) * N);
        half8* hB8 = hA8 + (N / 8);
        float tA[5], sA, tB[5], sB;
        #pragma unroll
        for (int j = 0; j < 4; ++j) {
            float4 qa0 = sA4[2 * lane + 128 * j], qa1 = sA4[2 * lane + 128 * j + 1];
            float4 qb0 = sB4[2 * lane + 128 * j], qb1 = sB4[2 * lane + 128 * j + 1];
            hA8[64 * j + lane] = pack_half8(qa0, qa1);
            hB8[64 * j + lane] = pack_half8(qb0, qb1);
            float zA[8] = {qa0.x*LOG2E, qa0.y*LOG2E, qa0.z*LOG2E, qa0.w*LOG2E,
                           qa1.x*LOG2E, qa1.y*LOG2E, qa1.z*LOG2E, qa1.w*LOG2E};
            float zB[8] = {qb0.x*LOG2E, qb0.y*LOG2E, qb0.z*LOG2E, qb0.w*LOG2E,
                           qb1.x*LOG2E, qb1.y*LOG2E, qb1.z*LOG2E, qb1.w*LOG2E};
            group_accum(j == 0, tA, sA, zA);
            group_accum(j == 0, tB, sB, zB);
        }

        #pragma unroll
        for (int off = 32; off >= 1; off >>= 1) merge5_shfl_xor2(tA, sA, tB, sB, off);

        online_add(tA, sA, alpha2);
        online_add(tB, sB, alpha2);

        float fA[16], fB[16], unA, unB;
        const float* ddA = dA + (size_t)(b * MP1 + r0) * 8;
        feats_from(tA, sA, -12.0f, ddA, fA, unA);
        feats_from(tB, sB, -12.0f, ddA + 8, fB, unB);

        float oA, oB;
        mlp_wave2(fA, fB, lane, w1, b1, g1, be1, w2, b2, g2, be2, w3, b3, oA, oB);
        if (lane == 0) {
            u[(size_t)b * UVS + r0]     = unA + oA * LOG2E;
            u[(size_t)b * UVS + r0 + 1] = unB + oB * LOG2E;
        }
    } else {
        // dustbin row r0 == M: all elements alpha2
        float t[5] = {alpha2, alpha2, alpha2, alpha2, alpha2};
        float s = 2049.0f;
        float f[16], un;
        const float* dd = dA + (size_t)(b * MP1 + M) * 8;
        feats_from(t, s, -1.0f, dd, f, un);
        float o = mlp_wave(f, lane, w1, b1, g1, be1, w2, b2, g2, be2, w3, b3);
        if (lane == 0) u[(size_t)b * UVS + M] = un + o * LOG2E;
    }
}

// ---------------------------------------------------------------------------
// fp16 transpose: sh[b][r][c] -> shT[b][c][r]. 64x64 LDS tiles. (unchanged)
// ---------------------------------------------------------------------------
__global__ __launch_bounds__(256) void transpose_half(
    const __half* __restrict__ sh, __half* __restrict__ shT)
{
    __shared__ unsigned short a[64][65];
    const int b  = blockIdx.z;
    const int r0 = blockIdx.x * 64;
    const int c0 = blockIdx.y * 64;
    const int t  = threadIdx.x;

    const __half* src = sh + ((size_t)b * M + r0) * N + c0;
    #pragma unroll
    for (int i = 0; i < 2; ++i) {
        int s = t + 256 * i;            // 512 half8 slots
        int r = s >> 3, c8 = (s & 7) * 8;
        half8 hv = *(const half8*)(src + (size_t)r * N + c8);
        const unsigned short* pv = (const unsigned short*)&hv;
        #pragma unroll
        for (int k = 0; k < 8; ++k) a[r][c8 + k] = pv[k];
    }
    __syncthreads();
    __half* dst = shT + ((size_t)b * N + c0) * M + r0;
    #pragma unroll
    for (int i = 0; i < 2; ++i) {
        int s = t + 256 * i;
        int c = s >> 3, r8 = (s & 7) * 8;
        half8 ov;
        unsigned short* po = (unsigned short*)&ov;
        #pragma unroll
        for (int k = 0; k < 8; ++k) po[k] = a[r8 + k][c];
        *(half8*)(dst + (size_t)c * M + r8) = ov;
    }
}

// ---------------------------------------------------------------------------
// Generic fp16 reduce + fused MLP pass (rows or cols). NEW STRUCTURE:
// grid (513, B), block 256 = 4 waves, ONE output per wave (2052 blocks:
// 8 blocks/CU -> up to 32 waves/CU). vk staged in LDS per block.
// Top5 butterfly has no exp2/s (merge5t); lse reconstructed from per-group
// (m_g, s_g) with one wave_sum. MLP uses fast fused-LN.
// ---------------------------------------------------------------------------
__global__ __launch_bounds__(256) void rc_fused(
    const __half* __restrict__ mat, const float* __restrict__ vk_base,
    const float* __restrict__ desc, const float* __restrict__ alpha,
    float* __restrict__ out,
    const float* __restrict__ w1, const float* __restrict__ b1,
    const float* __restrict__ g1, const float* __restrict__ be1,
    const float* __restrict__ w2, const float* __restrict__ b2,
    const float* __restrict__ g2, const float* __restrict__ be2,
    const float* __restrict__ w3, const float* __restrict__ b3)
{
    const int tid  = threadIdx.x;
    const int lane = tid & 63;
    const int wv   = tid >> 6;
    const int i    = blockIdx.x * 4 + wv;   // output index (row or col)
    const int b    = blockIdx.y;
    const float alpha2 = alpha[0] * LOG2E;
    const float* vk = vk_base + (size_t)b * UVS;

    // block-cooperative stage of vk[0..2051] into LDS (513 float4)
    __shared__ float svk[UVS];
    {
        const float4* src = (const float4*)vk;
        float4* dst = (float4*)svk;
        dst[tid]       = src[tid];
        dst[tid + 256] = src[tid + 256];
        if (tid == 0) dst[512] = src[512];
    }
    __syncthreads();
    if (i >= MP1) return;

    const float vkK = svk[K];
    const float4* sv4 = (const float4*)svk;

    float t[5], s;
    if (i < M) {
        const half8* h8 = (const half8*)(mat + ((size_t)b * M + i) * K);
        half8 ha[4];
        #pragma unroll
        for (int j = 0; j < 4; ++j) ha[j] = h8[64 * j + lane];

        float mg[4], sg[4];
        #pragma unroll
        for (int j = 0; j < 4; ++j) {
            float4 w0 = sv4[2 * lane + 128 * j];
            float4 w1v = sv4[2 * lane + 128 * j + 1];
            float2 a0 = __half22float2(ha[j].h[0]), a1 = __half22float2(ha[j].h[1]);
            float2 a2 = __half22float2(ha[j].h[2]), a3 = __half22float2(ha[j].h[3]);
            float z[8] = {fmaf(a0.x,LOG2E,w0.x),  fmaf(a0.y,LOG2E,w0.y),
                          fmaf(a1.x,LOG2E,w0.z),  fmaf(a1.y,LOG2E,w0.w),
                          fmaf(a2.x,LOG2E,w1v.x), fmaf(a2.y,LOG2E,w1v.y),
                          fmaf(a3.x,LOG2E,w1v.z), fmaf(a3.y,LOG2E,w1v.w)};
            group_accum_t(j == 0, t, z, mg[j], sg[j]);
        }

        // top5-only butterfly (no exp2 in the chain)
        #pragma unroll
        for (int off = 32; off >= 1; off >>= 1) merge5t_shfl_xor(t, off);

        // lse: per-lane rescaled group sums -> one wave reduction
        float m = t[0];
        float sl = 0.0f;
        #pragma unroll
        for (int j = 0; j < 4; ++j) sl = fmaf(sg[j], exp2g(mg[j] - m), sl);
        s = wave_sum(sl);
    } else {
        // dustbin output i == M: z[k] = alpha2 + vk[k]
        float mg[4], sg[4];
        #pragma unroll
        for (int j = 0; j < 4; ++j) {
            float4 w0 = sv4[2 * lane + 128 * j];
            float4 w1v = sv4[2 * lane + 128 * j + 1];
            float z[8] = {alpha2+w0.x,  alpha2+w0.y,  alpha2+w0.z,  alpha2+w0.w,
                          alpha2+w1v.x, alpha2+w1v.y, alpha2+w1v.z, alpha2+w1v.w};
            group_accum_t(j == 0, t, z, mg[j], sg[j]);
        }
        #pragma unroll
        for (int off = 32; off >= 1; off >>= 1) merge5t_shfl_xor(t, off);
        float m = t[0];
        float sl = 0.0f;
        #pragma unroll
        for (int j = 0; j < 4; ++j) sl = fmaf(sg[j], exp2g(mg[j] - m), sl);
        s = wave_sum(sl);
    }

    // dustbin element k == K
    online_add(t, s, alpha2 + vkK);

    float f[16], un;
    const float l2w = (i < M) ? -12.0f : -1.0f;
    const float* dd = desc + (size_t)(b * MP1 + i) * 8;
    feats_from(t, s, l2w, dd, f, un);

    float o = mlp_wave_fast(f, lane, w1, b1, g1, be1, w2, b2, g2, be2, w3, b3);
    if (lane == 0) out[(size_t)b * UVS + i] = un + o * LOG2E;
}

// ---------------------------------------------------------------------------
// out[b,r,c] = S*LOG2E + u[b,r] + v[b,c] + 12.  grid (2049, B), block 256.
// (unchanged)
// ---------------------------------------------------------------------------
__global__ __launch_bounds__(256) void final_kernel(
    const __half* __restrict__ sh, const float* __restrict__ alpha,
    const float* __restrict__ u, const float* __restrict__ v,
    float* __restrict__ out)
{
    const int r = blockIdx.x;
    const int b = blockIdx.y;
    const int tid = threadIdx.x;
    const float alpha2 = alpha[0] * LOG2E;
    const float* vb = v + (size_t)b * UVS;
    const float4* v4 = (const float4*)vb;
    const float ur = u[(size_t)b * UVS + r] + 12.0f;
    float* orow = out + ((size_t)b * MP1 + r) * MP1;

    float4 w0 = v4[2 * tid], w1v = v4[2 * tid + 1];
    const int c = tid * 8;
    if (r < M) {
        half8 hv = *(const half8*)(sh + ((size_t)b * M + r) * N + c);
        float2 a0 = __half22float2(hv.h[0]), a1 = __half22float2(hv.h[1]);
        float2 a2 = __half22float2(hv.h[2]), a3 = __half22float2(hv.h[3]);
        orow[c]     = fmaf(a0.x, LOG2E, ur + w0.x);
        orow[c + 1] = fmaf(a0.y, LOG2E, ur + w0.y);
        orow[c + 2] = fmaf(a1.x, LOG2E, ur + w0.z);
        orow[c + 3] = fmaf(a1.y, LOG2E, ur + w0.w);
        orow[c + 4] = fmaf(a2.x, LOG2E, ur + w1v.x);
        orow[c + 5] = fmaf(a2.y, LOG2E, ur + w1v.y);
        orow[c + 6] = fmaf(a3.x, LOG2E, ur + w1v.z);
        orow[c + 7] = fmaf(a3.y, LOG2E, ur + w1v.w);
    } else {
        orow[c]     = alpha2 + ur + w0.x;
        orow[c + 1] = alpha2 + ur + w0.y;
        orow[c + 2] = alpha2 + ur + w0.z;
        orow[c + 3] = alpha2 + ur + w0.w;
        orow[c + 4] = alpha2 + ur + w1v.x;
        orow[c + 5] = alpha2 + ur + w1v.y;
        orow[c + 6] = alpha2 + ur + w1v.z;
        orow[c + 7] = alpha2 + ur + w1v.w;
    }
    if (tid == 0) orow[N] = alpha2 + ur + vb[N];
}

extern "C" void kernel_launch(void* const* d_in, const int* in_sizes, int n_in,
                              void* d_out, int out_size, void* d_ws, size_t ws_size,
                              hipStream_t stream) {
    const float* scores = (const float*)d_in[0];
    const float* alpha  = (const float*)d_in[1];
    const float* mdesc0 = (const float*)d_in[2];
    const float* mdesc1 = (const float*)d_in[3];
    const float* pA_w = (const float*)d_in[4];
    const float* pA_b = (const float*)d_in[5];
    const float* pB_w = (const float*)d_in[6];
    const float* pB_b = (const float*)d_in[7];
    const float* rW[10]; const float* cW[10];
    for (int k = 0; k < 10; ++k) rW[k] = (const float*)d_in[8 + k];
    for (int k = 0; k < 10; ++k) cW[k] = (const float*)d_in[18 + k];
    float* out = (float*)d_out;

    const int B = in_sizes[0] / (M * N);

    float* ws = (float*)d_ws;
    float* u     = ws;                              // B*UVS
    float* v     = u + (size_t)B * UVS;             // B*UVS
    float* dA    = v + (size_t)B * UVS;             // B*MP1*8
    float* dB    = dA + (size_t)B * MP1 * 8;        // B*MP1*8
    float* ppart = dB + (size_t)B * MP1 * 8;        // 2*B*MP1*64
    __half* sh   = (__half*)(ppart + (size_t)2 * B * MP1 * 64); // B*M*N halfs
    __half* shT  = sh + (size_t)B * M * N;                      // B*N*M halfs

    const int CB = (MP1 + 255) / 256;           // 9
    const int PB = ((MP1 + 1) / 2 + 3) / 4;     // 257: row0 (2 rows per wave)
    const int RB = (MP1 + 3) / 4;               // 513: rc_fused (1 output per wave)

    proj_part<<<dim3(CB, B, 16), 256, 0, stream>>>(
        mdesc0, mdesc1, pA_w, pB_w, ppart, B);
    proj_combine<<<dim3(CB, B, 2), 256, 0, stream>>>(
        ppart, pA_b, pB_b, dA, dB, B);

    // iter 0: row pass on fp32 (v == 0), produce sh; transpose; col pass
    row0_fused<<<dim3(PB, B), 256, 0, stream>>>(
        scores, sh, alpha, dA, u,
        rW[0], rW[1], rW[2], rW[3], rW[4], rW[5], rW[6], rW[7], rW[8], rW[9]);
    transpose_half<<<dim3(32, 32, B), 256, 0, stream>>>(sh, shT);
    rc_fused<<<dim3(RB, B), 256, 0, stream>>>(
        shT, u, dB, alpha, v,
        cW[0], cW[1], cW[2], cW[3], cW[4], cW[5], cW[6], cW[7], cW[8], cW[9]);

    for (int it = 1; it < 3; ++it) {
        rc_fused<<<dim3(RB, B), 256, 0, stream>>>(
            sh, v, dA, alpha, u,
            rW[0], rW[1], rW[2], rW[3], rW[4], rW[5], rW[6], rW[7], rW[8], rW[9]);
        rc_fused<<<dim3(RB, B), 256, 0, stream>>>(
            shT, u, dB, alpha, v,
            cW[0], cW[1], cW[2], cW[3], cW[4], cW[5], cW[6], cW[7], cW[8], cW[9]);
    }
    final_kernel<<<dim3(MP1, B), 256, 0, stream>>>(sh, alpha, u, v, out);
}

// Round 7
// 336.699 us; speedup vs baseline: 1.0618x; 1.0618x over previous
//
#include <hip/hip_runtime.h>
#include <hip/hip_fp16.h>
#include <math.h>

#define LOG2E 1.4426950408889634f
#define LN2F  0.6931471805599453f

constexpr int M   = 2048;
constexpr int N   = 2048;
constexpr int D   = 256;
constexpr int K   = 2048;   // reduce length (both directions)
constexpr int MP1 = 2049;   // M+1 == N+1
constexpr int UVS = 2052;   // padded u/v batch stride -> float4-aligned rows

struct alignas(16) half8 { __half2 h[4]; };

__device__ inline half8 pack_half8(const float4& a, const float4& b) {
    half8 r;
    r.h[0] = __floats2half2_rn(a.x, a.y);
    r.h[1] = __floats2half2_rn(a.z, a.w);
    r.h[2] = __floats2half2_rn(b.x, b.y);
    r.h[3] = __floats2half2_rn(b.z, b.w);
    return r;
}

__device__ inline float fast_exp2(float x) {
#if __has_builtin(__builtin_amdgcn_exp2f)
    return __builtin_amdgcn_exp2f(x);
#else
    return exp2f(x);
#endif
}
__device__ inline float fast_log2(float x) {
#if __has_builtin(__builtin_amdgcn_logf)
    return __builtin_amdgcn_logf(x);   // v_log_f32 is log2
#else
    return log2f(x);
#endif
}
// NaN-guarded exp2 for identity (-inf) merges
__device__ inline float exp2g(float x) { return fast_exp2(fmaxf(x, -20000.0f)); }

__device__ inline void insert5(float t[5], float y) {
    float v = y, mx;
    #pragma unroll
    for (int k = 0; k < 5; ++k) { mx = fmaxf(t[k], v); v = fminf(t[k], v); t[k] = mx; }
}

__device__ inline void ce_desc(float& a, float& b) {
    float hi = fmaxf(a, b), lo = fminf(a, b); a = hi; b = lo;
}
// 19-CE sorting network for 8 elements, descending (y[0] = max).
__device__ inline void sort8_desc(float y[8]) {
    ce_desc(y[0],y[1]); ce_desc(y[2],y[3]); ce_desc(y[4],y[5]); ce_desc(y[6],y[7]);
    ce_desc(y[0],y[2]); ce_desc(y[1],y[3]); ce_desc(y[4],y[6]); ce_desc(y[5],y[7]);
    ce_desc(y[1],y[2]); ce_desc(y[5],y[6]); ce_desc(y[0],y[4]); ce_desc(y[3],y[7]);
    ce_desc(y[1],y[5]); ce_desc(y[2],y[6]);
    ce_desc(y[1],y[4]); ce_desc(y[3],y[6]);
    ce_desc(y[2],y[4]); ce_desc(y[3],y[5]);
    ce_desc(y[3],y[4]);
}

// top5-only merge: no lse state, no exp2 -- pure min/max network
__device__ inline void merge5t(float a[5], const float b[5]) {
    float r0 = fmaxf(a[0], b[0]);
    float r1 = fmaxf(fmaxf(a[1], b[1]), fminf(a[0], b[0]));
    float r2 = fmaxf(fmaxf(a[2], b[2]), fmaxf(fminf(a[1], b[0]), fminf(a[0], b[1])));
    float r3 = fmaxf(fmaxf(a[3], b[3]),
               fmaxf(fmaxf(fminf(a[2], b[0]), fminf(a[1], b[1])), fminf(a[0], b[2])));
    float r4 = fmaxf(fmaxf(a[4], b[4]),
               fmaxf(fmaxf(fminf(a[3], b[0]), fminf(a[2], b[1])),
                     fmaxf(fminf(a[1], b[2]), fminf(a[0], b[3]))));
    a[0] = r0; a[1] = r1; a[2] = r2; a[3] = r3; a[4] = r4;
}

__device__ inline void merge5t_shfl_xor(float t[5], int off) {
    float b[5];
    #pragma unroll
    for (int k = 0; k < 5; ++k) b[k] = __shfl_xor(t[k], off, 64);
    merge5t(t, b);
}

// dual top5-only butterfly level
__device__ inline void merge5t_shfl_xor2(float tA[5], float tB[5], int off) {
    float bA[5], bB[5];
    #pragma unroll
    for (int k = 0; k < 5; ++k) { bA[k] = __shfl_xor(tA[k], off, 64); bB[k] = __shfl_xor(tB[k], off, 64); }
    merge5t(tA, bA);
    merge5t(tB, bB);
}

__device__ inline void online_add(float t[5], float& s, float y) {
    float m_old = t[0];
    float m_new = fmaxf(m_old, y);
    s = s * exp2g(m_old - m_new) + fast_exp2(y - m_new);
    insert5(t, y);
}

// sort group of 8, record per-group (max, sum-at-max), fold top5 only
__device__ inline void group_accum_t(bool first, float t[5], float z[8],
                                     float& mgv, float& sgv) {
    sort8_desc(z);
    float gs = 1.0f;
    #pragma unroll
    for (int k = 1; k < 8; ++k) gs += fast_exp2(z[k] - z[0]);
    mgv = z[0]; sgv = gs;
    if (first) { t[0]=z[0]; t[1]=z[1]; t[2]=z[2]; t[3]=z[3]; t[4]=z[4]; }
    else merge5t(t, z);
}

__device__ inline float gelu_exact(float x) {
    return 0.5f * x * (1.0f + erff(x * 0.70710678118654752f));
}

__device__ inline float wave_sum(float x) {
    #pragma unroll
    for (int off = 32; off >= 1; off >>= 1) x += __shfl_xor(x, off, 64);
    return x;
}
__device__ inline void wave_sum2(float& x, float& y) {
    #pragma unroll
    for (int off = 32; off >= 1; off >>= 1) {
        float xs = __shfl_xor(x, off, 64);
        float ys = __shfl_xor(y, off, 64);
        x += xs; y += ys;
    }
}
__device__ inline void wave_sum4(float& a, float& b, float& c, float& d) {
    #pragma unroll
    for (int off = 32; off >= 1; off >>= 1) {
        float as = __shfl_xor(a, off, 64);
        float bs = __shfl_xor(b, off, 64);
        float cs = __shfl_xor(c, off, 64);
        float ds = __shfl_xor(d, off, 64);
        a += as; b += bs; c += cs; d += ds;
    }
}

// one-wave MLP, fused-moment LN (single wave_sum2 of (sum, sumsq) per LN).
__device__ inline float mlp_wave_fast(const float f[16], int j,
    const float* __restrict__ w1, const float* __restrict__ b1,
    const float* __restrict__ g1, const float* __restrict__ be1,
    const float* __restrict__ w2, const float* __restrict__ b2,
    const float* __restrict__ g2, const float* __restrict__ be2,
    const float* __restrict__ w3, const float* __restrict__ b3)
{
    float h = b1[j];
    #pragma unroll
    for (int k = 0; k < 16; ++k) h = fmaf(f[k], w1[j * 16 + k], h);
    h = gelu_exact(h);
    float sm = h, sq = h * h;
    wave_sum2(sm, sq);
    float mu  = sm * (1.0f / 64.0f);
    float var = sq * (1.0f / 64.0f) - mu * mu;
    float hn  = (h - mu) * rsqrtf(var + 1e-5f) * g1[j] + be1[j];

    float a0 = b2[j], a1 = 0.0f;
    #pragma unroll
    for (int k = 0; k < 64; k += 2) {
        a0 = fmaf(__shfl(hn, k, 64),     w2[j * 64 + k],     a0);
        a1 = fmaf(__shfl(hn, k + 1, 64), w2[j * 64 + k + 1], a1);
    }
    float h2 = gelu_exact(a0 + a1);
    sm = h2; sq = h2 * h2;
    wave_sum2(sm, sq);
    mu  = sm * (1.0f / 64.0f);
    var = sq * (1.0f / 64.0f) - mu * mu;
    float hn2 = (h2 - mu) * rsqrtf(var + 1e-5f) * g2[j] + be2[j];
    return wave_sum(hn2 * w3[j]) + b3[0];
}

// dual MLP, fused-moment LN via wave_sum4 (both rows' (sum,sumsq) in one butterfly)
__device__ inline void mlp_wave2_fast(const float fA[16], const float fB[16], int j,
    const float* __restrict__ w1, const float* __restrict__ b1,
    const float* __restrict__ g1, const float* __restrict__ be1,
    const float* __restrict__ w2, const float* __restrict__ b2,
    const float* __restrict__ g2, const float* __restrict__ be2,
    const float* __restrict__ w3, const float* __restrict__ b3,
    float& oA, float& oB)
{
    float hA = b1[j], hB = hA;
    #pragma unroll
    for (int k = 0; k < 16; ++k) {
        float w = w1[j * 16 + k];
        hA = fmaf(fA[k], w, hA);
        hB = fmaf(fB[k], w, hB);
    }
    hA = gelu_exact(hA); hB = gelu_exact(hB);
    float smA = hA, sqA = hA * hA, smB = hB, sqB = hB * hB;
    wave_sum4(smA, sqA, smB, sqB);
    float muA = smA * (1.0f / 64.0f), muB = smB * (1.0f / 64.0f);
    float vA  = sqA * (1.0f / 64.0f) - muA * muA;
    float vB  = sqB * (1.0f / 64.0f) - muB * muB;
    float hnA = (hA - muA) * rsqrtf(vA + 1e-5f) * g1[j] + be1[j];
    float hnB = (hB - muB) * rsqrtf(vB + 1e-5f) * g1[j] + be1[j];

    float a0A = b2[j], a1A = 0.0f, a0B = b2[j], a1B = 0.0f;
    #pragma unroll
    for (int k = 0; k < 64; k += 2) {
        float w0 = w2[j * 64 + k], w1v = w2[j * 64 + k + 1];
        float sA0 = __shfl(hnA, k, 64),     sB0 = __shfl(hnB, k, 64);
        float sA1 = __shfl(hnA, k + 1, 64), sB1 = __shfl(hnB, k + 1, 64);
        a0A = fmaf(sA0, w0, a0A); a0B = fmaf(sB0, w0, a0B);
        a1A = fmaf(sA1, w1v, a1A); a1B = fmaf(sB1, w1v, a1B);
    }
    float h2A = gelu_exact(a0A + a1A), h2B = gelu_exact(a0B + a1B);
    smA = h2A; sqA = h2A * h2A; smB = h2B; sqB = h2B * h2B;
    wave_sum4(smA, sqA, smB, sqB);
    muA = smA * (1.0f / 64.0f); muB = smB * (1.0f / 64.0f);
    vA  = sqA * (1.0f / 64.0f) - muA * muA;
    vB  = sqB * (1.0f / 64.0f) - muB * muB;
    float hn2A = (h2A - muA) * rsqrtf(vA + 1e-5f) * g2[j] + be2[j];
    float hn2B = (h2B - muB) * rsqrtf(vB + 1e-5f) * g2[j] + be2[j];
    float zA = hn2A * w3[j], zB = hn2B * w3[j];
    wave_sum2(zA, zB);
    oA = zA + b3[0];
    oB = zB + b3[0];
}

__device__ inline void feats_from(const float t[5], float s, float l2w,
                                  const float* __restrict__ dd, float f[16], float& un)
{
    float lse = t[0] + fast_log2(s);
    un = l2w - lse;
    f[0] = l2w * LN2F;
    f[1] = un  * LN2F;
    f[2] = 0.0f;
    f[3] = (t[0] - t[1]) * LN2F;
    f[4] = (t[0] - t[2]) * LN2F;
    f[5] = (t[0] - t[3]) * LN2F;
    f[6] = (t[0] - t[4]) * LN2F;
    f[7] = (lse - t[0]) * LN2F;
    #pragma unroll
    for (int p = 0; p < 8; ++p) f[8 + p] = dd[p];
}

// ---------------------------------------------------------------------------
// proj, K-split: grid (9, B, 16) [z = which*8 + ks], block 256. (unchanged)
// ---------------------------------------------------------------------------
__global__ __launch_bounds__(256) void proj_part(
    const float* __restrict__ mdesc0, const float* __restrict__ mdesc1,
    const float* __restrict__ pA_w, const float* __restrict__ pB_w,
    float* __restrict__ ppart, int B)
{
    const int which = blockIdx.z >> 3;
    const int ks    = blockIdx.z & 7;
    const float* mdesc = which ? mdesc1 : mdesc0;
    const float* pw    = which ? pB_w : pA_w;

    __shared__ float swT[32 * 8];   // swT[d0*8+p]
    const int tid = threadIdx.x;
    {
        int p = tid >> 5, d0 = tid & 31;
        swT[d0 * 8 + p] = pw[p * D + ks * 32 + d0];
    }
    __syncthreads();

    const int m = blockIdx.x * 256 + tid;
    const int b = blockIdx.y;
    if (m >= M) return;

    float acc[8];
    #pragma unroll
    for (int p = 0; p < 8; ++p) acc[p] = 0.0f;
    const float* base = mdesc + ((size_t)b * D + ks * 32) * M + m;
    #pragma unroll 4
    for (int d0 = 0; d0 < 32; ++d0) {
        float x = base[(size_t)d0 * M];
        #pragma unroll
        for (int p = 0; p < 8; ++p) acc[p] = fmaf(x, swT[d0 * 8 + p], acc[p]);
    }
    float4* o = (float4*)(ppart + (((size_t)(which * B + b)) * MP1 + m) * 64 + ks * 8);
    o[0] = make_float4(acc[0], acc[1], acc[2], acc[3]);
    o[1] = make_float4(acc[4], acc[5], acc[6], acc[7]);
}

// grid (9, B, 2), block 256: sum 8 K-partials + bias; dustbin row m==M -> 0
__global__ __launch_bounds__(256) void proj_combine(
    const float* __restrict__ ppart,
    const float* __restrict__ pA_b, const float* __restrict__ pB_b,
    float* __restrict__ dA, float* __restrict__ dB, int B)
{
    const int which = blockIdx.z;
    const float* pb = which ? pB_b : pA_b;
    float* dOut     = which ? dB   : dA;
    const int m = blockIdx.x * 256 + threadIdx.x;
    const int b = blockIdx.y;
    if (m > M) return;
    float* out = dOut + ((size_t)b * MP1 + m) * 8;
    if (m == M) {
        #pragma unroll
        for (int p = 0; p < 8; ++p) out[p] = 0.0f;
        return;
    }
    float acc[8];
    #pragma unroll
    for (int p = 0; p < 8; ++p) acc[p] = pb[p];
    const float4* pp = (const float4*)(ppart + (((size_t)(which * B + b)) * MP1 + m) * 64);
    #pragma unroll
    for (int ks = 0; ks < 8; ++ks) {
        float4 x0 = pp[2 * ks], x1 = pp[2 * ks + 1];
        acc[0] += x0.x; acc[1] += x0.y; acc[2] += x0.z; acc[3] += x0.w;
        acc[4] += x1.x; acc[5] += x1.y; acc[6] += x1.z; acc[7] += x1.w;
    }
    #pragma unroll
    for (int p = 0; p < 8; ++p) out[p] = acc[p];
}

// ---------------------------------------------------------------------------
// Iter-0 row pass: reads fp32 scores (v==0), writes fp16 copy sh, fused MLP.
// grid (257, B), block 256 = 4 waves, TWO rows per wave.
// Split-lse butterfly + fused-moment LN.
// ---------------------------------------------------------------------------
__global__ __launch_bounds__(256) void row0_fused(
    const float* __restrict__ scores, __half* __restrict__ sh,
    const float* __restrict__ alpha, const float* __restrict__ dA,
    float* __restrict__ u,
    const float* __restrict__ w1, const float* __restrict__ b1,
    const float* __restrict__ g1, const float* __restrict__ be1,
    const float* __restrict__ w2, const float* __restrict__ b2,
    const float* __restrict__ g2, const float* __restrict__ be2,
    const float* __restrict__ w3, const float* __restrict__ b3)
{
    const int tid  = threadIdx.x;
    const int lane = tid & 63;
    const int wv   = tid >> 6;
    const int pair = blockIdx.x * 4 + wv;
    const int r0   = pair * 2;
    if (r0 >= MP1) return;
    const int b = blockIdx.y;
    const float alpha2 = alpha[0] * LOG2E;

    if (r0 < M) {
        const float4* sA4 = (const float4*)(scores + ((size_t)b * M + r0) * N);
        const float4* sB4 = sA4 + (N / 4);
        half8* hA8 = (half8*)(sh + ((size_t)b * M + r0) * N);
        half8* hB8 = hA8 + (N / 8);
        float tA[5], tB[5];
        float mgA[4], sgA[4], mgB[4], sgB[4];
        #pragma unroll
        for (int j = 0; j < 4; ++j) {
            float4 qa0 = sA4[2 * lane + 128 * j], qa1 = sA4[2 * lane + 128 * j + 1];
            float4 qb0 = sB4[2 * lane + 128 * j], qb1 = sB4[2 * lane + 128 * j + 1];
            hA8[64 * j + lane] = pack_half8(qa0, qa1);
            hB8[64 * j + lane] = pack_half8(qb0, qb1);
            float zA[8] = {qa0.x*LOG2E, qa0.y*LOG2E, qa0.z*LOG2E, qa0.w*LOG2E,
                           qa1.x*LOG2E, qa1.y*LOG2E, qa1.z*LOG2E, qa1.w*LOG2E};
            float zB[8] = {qb0.x*LOG2E, qb0.y*LOG2E, qb0.z*LOG2E, qb0.w*LOG2E,
                           qb1.x*LOG2E, qb1.y*LOG2E, qb1.z*LOG2E, qb1.w*LOG2E};
            group_accum_t(j == 0, tA, zA, mgA[j], sgA[j]);
            group_accum_t(j == 0, tB, zB, mgB[j], sgB[j]);
        }

        // top5-only dual butterfly (no exp2, no s in the chain)
        #pragma unroll
        for (int off = 32; off >= 1; off >>= 1) merge5t_shfl_xor2(tA, tB, off);

        // lse reconstruction: per-lane rescaled group sums, one dual wave-sum
        float mA = tA[0], mB = tB[0];
        float slA = 0.0f, slB = 0.0f;
        #pragma unroll
        for (int j = 0; j < 4; ++j) {
            slA = fmaf(sgA[j], exp2g(mgA[j] - mA), slA);
            slB = fmaf(sgB[j], exp2g(mgB[j] - mB), slB);
        }
        wave_sum2(slA, slB);
        float sA = slA, sB = slB;

        online_add(tA, sA, alpha2);
        online_add(tB, sB, alpha2);

        float fA[16], fB[16], unA, unB;
        const float* ddA = dA + (size_t)(b * MP1 + r0) * 8;
        feats_from(tA, sA, -12.0f, ddA, fA, unA);
        feats_from(tB, sB, -12.0f, ddA + 8, fB, unB);

        float oA, oB;
        mlp_wave2_fast(fA, fB, lane, w1, b1, g1, be1, w2, b2, g2, be2, w3, b3, oA, oB);
        if (lane == 0) {
            u[(size_t)b * UVS + r0]     = unA + oA * LOG2E;
            u[(size_t)b * UVS + r0 + 1] = unB + oB * LOG2E;
        }
    } else {
        // dustbin row r0 == M: all elements alpha2
        float t[5] = {alpha2, alpha2, alpha2, alpha2, alpha2};
        float s = 2049.0f;
        float f[16], un;
        const float* dd = dA + (size_t)(b * MP1 + M) * 8;
        feats_from(t, s, -1.0f, dd, f, un);
        float o = mlp_wave_fast(f, lane, w1, b1, g1, be1, w2, b2, g2, be2, w3, b3);
        if (lane == 0) u[(size_t)b * UVS + M] = un + o * LOG2E;
    }
}

// ---------------------------------------------------------------------------
// fp16 transpose: sh[b][r][c] -> shT[b][c][r]. 64x64 LDS tiles. (unchanged)
// ---------------------------------------------------------------------------
__global__ __launch_bounds__(256) void transpose_half(
    const __half* __restrict__ sh, __half* __restrict__ shT)
{
    __shared__ unsigned short a[64][65];
    const int b  = blockIdx.z;
    const int r0 = blockIdx.x * 64;
    const int c0 = blockIdx.y * 64;
    const int t  = threadIdx.x;

    const __half* src = sh + ((size_t)b * M + r0) * N + c0;
    #pragma unroll
    for (int i = 0; i < 2; ++i) {
        int s = t + 256 * i;            // 512 half8 slots
        int r = s >> 3, c8 = (s & 7) * 8;
        half8 hv = *(const half8*)(src + (size_t)r * N + c8);
        const unsigned short* pv = (const unsigned short*)&hv;
        #pragma unroll
        for (int k = 0; k < 8; ++k) a[r][c8 + k] = pv[k];
    }
    __syncthreads();
    __half* dst = shT + ((size_t)b * N + c0) * M + r0;
    #pragma unroll
    for (int i = 0; i < 2; ++i) {
        int s = t + 256 * i;
        int c = s >> 3, r8 = (s & 7) * 8;
        half8 ov;
        unsigned short* po = (unsigned short*)&ov;
        #pragma unroll
        for (int k = 0; k < 8; ++k) po[k] = a[r8 + k][c];
        *(half8*)(dst + (size_t)c * M + r8) = ov;
    }
}

// ---------------------------------------------------------------------------
// Generic fp16 reduce + fused MLP pass (rows or cols). Round-5 structure
// (grid (257,B), 4 waves/block, TWO outputs per wave, direct vk loads,
// no LDS, no barrier) + split-lse butterfly + fused-moment LN MLP.
// ---------------------------------------------------------------------------
__global__ __launch_bounds__(256) void rc_fused(
    const __half* __restrict__ mat, const float* __restrict__ vk_base,
    const float* __restrict__ desc, const float* __restrict__ alpha,
    float* __restrict__ out,
    const float* __restrict__ w1, const float* __restrict__ b1,
    const float* __restrict__ g1, const float* __restrict__ be1,
    const float* __restrict__ w2, const float* __restrict__ b2,
    const float* __restrict__ g2, const float* __restrict__ be2,
    const float* __restrict__ w3, const float* __restrict__ b3)
{
    const int tid  = threadIdx.x;
    const int lane = tid & 63;
    const int wv   = tid >> 6;
    const int pair = blockIdx.x * 4 + wv;
    const int i0   = pair * 2;
    if (i0 >= MP1) return;
    const int b = blockIdx.y;
    const float alpha2 = alpha[0] * LOG2E;
    const float* vk = vk_base + (size_t)b * UVS;
    const float4* vk4 = (const float4*)vk;

    if (i0 < M) {
        const half8* hA8 = (const half8*)(mat + ((size_t)b * M + i0) * K);
        const half8* hB8 = hA8 + (K / 8);
        half8 ha[4], hb[4];
        float4 vv[8];
        #pragma unroll
        for (int j = 0; j < 4; ++j) { ha[j] = hA8[64 * j + lane]; hb[j] = hB8[64 * j + lane]; }
        #pragma unroll
        for (int j = 0; j < 4; ++j) {
            vv[2 * j]     = vk4[2 * lane + 128 * j];
            vv[2 * j + 1] = vk4[2 * lane + 128 * j + 1];
        }
        float tA[5], tB[5];
        float mgA[4], sgA[4], mgB[4], sgB[4];
        #pragma unroll
        for (int j = 0; j < 4; ++j) {
            float2 a0 = __half22float2(ha[j].h[0]), a1 = __half22float2(ha[j].h[1]);
            float2 a2 = __half22float2(ha[j].h[2]), a3 = __half22float2(ha[j].h[3]);
            float2 b0 = __half22float2(hb[j].h[0]), b1v = __half22float2(hb[j].h[1]);
            float2 b2v = __half22float2(hb[j].h[2]), b3v = __half22float2(hb[j].h[3]);
            float4 w0 = vv[2 * j], w1v = vv[2 * j + 1];
            float zA[8] = {fmaf(a0.x,LOG2E,w0.x),  fmaf(a0.y,LOG2E,w0.y),
                           fmaf(a1.x,LOG2E,w0.z),  fmaf(a1.y,LOG2E,w0.w),
                           fmaf(a2.x,LOG2E,w1v.x), fmaf(a2.y,LOG2E,w1v.y),
                           fmaf(a3.x,LOG2E,w1v.z), fmaf(a3.y,LOG2E,w1v.w)};
            float zB[8] = {fmaf(b0.x,LOG2E,w0.x),  fmaf(b0.y,LOG2E,w0.y),
                           fmaf(b1v.x,LOG2E,w0.z), fmaf(b1v.y,LOG2E,w0.w),
                           fmaf(b2v.x,LOG2E,w1v.x), fmaf(b2v.y,LOG2E,w1v.y),
                           fmaf(b3v.x,LOG2E,w1v.z), fmaf(b3v.y,LOG2E,w1v.w)};
            group_accum_t(j == 0, tA, zA, mgA[j], sgA[j]);
            group_accum_t(j == 0, tB, zB, mgB[j], sgB[j]);
        }

        // top5-only dual butterfly
        #pragma unroll
        for (int off = 32; off >= 1; off >>= 1) merge5t_shfl_xor2(tA, tB, off);

        // lse reconstruction
        float mA = tA[0], mB = tB[0];
        float slA = 0.0f, slB = 0.0f;
        #pragma unroll
        for (int j = 0; j < 4; ++j) {
            slA = fmaf(sgA[j], exp2g(mgA[j] - mA), slA);
            slB = fmaf(sgB[j], exp2g(mgB[j] - mB), slB);
        }
        wave_sum2(slA, slB);
        float sA = slA, sB = slB;

        float extra = alpha2 + vk[K];
        online_add(tA, sA, extra);
        online_add(tB, sB, extra);

        float fA[16], fB[16], unA, unB;
        const float* ddA = desc + (size_t)(b * MP1 + i0) * 8;
        feats_from(tA, sA, -12.0f, ddA, fA, unA);
        feats_from(tB, sB, -12.0f, ddA + 8, fB, unB);

        float oA, oB;
        mlp_wave2_fast(fA, fB, lane, w1, b1, g1, be1, w2, b2, g2, be2, w3, b3, oA, oB);
        if (lane == 0) {
            out[(size_t)b * UVS + i0]     = unA + oA * LOG2E;
            out[(size_t)b * UVS + i0 + 1] = unB + oB * LOG2E;
        }
    } else {
        // dustbin output i0 == M: z[k] = alpha2 + vk[k]
        float t[5];
        float mg[4], sg[4];
        #pragma unroll
        for (int g = 0; g < 4; ++g) {
            float4 wa = vk4[lane + 128 * g];
            float4 wb = vk4[lane + 128 * g + 64];
            float z[8] = {alpha2+wa.x, alpha2+wa.y, alpha2+wa.z, alpha2+wa.w,
                          alpha2+wb.x, alpha2+wb.y, alpha2+wb.z, alpha2+wb.w};
            group_accum_t(g == 0, t, z, mg[g], sg[g]);
        }
        #pragma unroll
        for (int off = 32; off >= 1; off >>= 1) merge5t_shfl_xor(t, off);
        float m = t[0];
        float sl = 0.0f;
        #pragma unroll
        for (int g = 0; g < 4; ++g) sl = fmaf(sg[g], exp2g(mg[g] - m), sl);
        float s = wave_sum(sl);
        online_add(t, s, alpha2 + vk[K]);

        float f[16], un;
        const float* dd = desc + (size_t)(b * MP1 + M) * 8;
        feats_from(t, s, -1.0f, dd, f, un);
        float o = mlp_wave_fast(f, lane, w1, b1, g1, be1, w2, b2, g2, be2, w3, b3);
        if (lane == 0) out[(size_t)b * UVS + M] = un + o * LOG2E;
    }
}

// ---------------------------------------------------------------------------
// out[b,r,c] = S*LOG2E + u[b,r] + v[b,c] + 12.  grid (2049, B), block 256.
// (unchanged)
// ---------------------------------------------------------------------------
__global__ __launch_bounds__(256) void final_kernel(
    const __half* __restrict__ sh, const float* __restrict__ alpha,
    const float* __restrict__ u, const float* __restrict__ v,
    float* __restrict__ out)
{
    const int r = blockIdx.x;
    const int b = blockIdx.y;
    const int tid = threadIdx.x;
    const float alpha2 = alpha[0] * LOG2E;
    const float* vb = v + (size_t)b * UVS;
    const float4* v4 = (const float4*)vb;
    const float ur = u[(size_t)b * UVS + r] + 12.0f;
    float* orow = out + ((size_t)b * MP1 + r) * MP1;

    float4 w0 = v4[2 * tid], w1v = v4[2 * tid + 1];
    const int c = tid * 8;
    if (r < M) {
        half8 hv = *(const half8*)(sh + ((size_t)b * M + r) * N + c);
        float2 a0 = __half22float2(hv.h[0]), a1 = __half22float2(hv.h[1]);
        float2 a2 = __half22float2(hv.h[2]), a3 = __half22float2(hv.h[3]);
        orow[c]     = fmaf(a0.x, LOG2E, ur + w0.x);
        orow[c + 1] = fmaf(a0.y, LOG2E, ur + w0.y);
        orow[c + 2] = fmaf(a1.x, LOG2E, ur + w0.z);
        orow[c + 3] = fmaf(a1.y, LOG2E, ur + w0.w);
        orow[c + 4] = fmaf(a2.x, LOG2E, ur + w1v.x);
        orow[c + 5] = fmaf(a2.y, LOG2E, ur + w1v.y);
        orow[c + 6] = fmaf(a3.x, LOG2E, ur + w1v.z);
        orow[c + 7] = fmaf(a3.y, LOG2E, ur + w1v.w);
    } else {
        orow[c]     = alpha2 + ur + w0.x;
        orow[c + 1] = alpha2 + ur + w0.y;
        orow[c + 2] = alpha2 + ur + w0.z;
        orow[c + 3] = alpha2 + ur + w0.w;
        orow[c + 4] = alpha2 + ur + w1v.x;
        orow[c + 5] = alpha2 + ur + w1v.y;
        orow[c + 6] = alpha2 + ur + w1v.z;
        orow[c + 7] = alpha2 + ur + w1v.w;
    }
    if (tid == 0) orow[N] = alpha2 + ur + vb[N];
}

extern "C" void kernel_launch(void* const* d_in, const int* in_sizes, int n_in,
                              void* d_out, int out_size, void* d_ws, size_t ws_size,
                              hipStream_t stream) {
    const float* scores = (const float*)d_in[0];
    const float* alpha  = (const float*)d_in[1];
    const float* mdesc0 = (const float*)d_in[2];
    const float* mdesc1 = (const float*)d_in[3];
    const float* pA_w = (const float*)d_in[4];
    const float* pA_b = (const float*)d_in[5];
    const float* pB_w = (const float*)d_in[6];
    const float* pB_b = (const float*)d_in[7];
    const float* rW[10]; const float* cW[10];
    for (int k = 0; k < 10; ++k) rW[k] = (const float*)d_in[8 + k];
    for (int k = 0; k < 10; ++k) cW[k] = (const float*)d_in[18 + k];
    float* out = (float*)d_out;

    const int B = in_sizes[0] / (M * N);

    float* ws = (float*)d_ws;
    float* u     = ws;                              // B*UVS
    float* v     = u + (size_t)B * UVS;             // B*UVS
    float* dA    = v + (size_t)B * UVS;             // B*MP1*8
    float* dB    = dA + (size_t)B * MP1 * 8;        // B*MP1*8
    float* ppart = dB + (size_t)B * MP1 * 8;        // 2*B*MP1*64
    __half* sh   = (__half*)(ppart + (size_t)2 * B * MP1 * 64); // B*M*N halfs
    __half* shT  = sh + (size_t)B * M * N;                      // B*N*M halfs

    const int CB = (MP1 + 255) / 256;           // 9
    const int PB = ((MP1 + 1) / 2 + 3) / 4;     // 257: 2 outputs per wave

    proj_part<<<dim3(CB, B, 16), 256, 0, stream>>>(
        mdesc0, mdesc1, pA_w, pB_w, ppart, B);
    proj_combine<<<dim3(CB, B, 2), 256, 0, stream>>>(
        ppart, pA_b, pB_b, dA, dB, B);

    // iter 0: row pass on fp32 (v == 0), produce sh; transpose; col pass
    row0_fused<<<dim3(PB, B), 256, 0, stream>>>(
        scores, sh, alpha, dA, u,
        rW[0], rW[1], rW[2], rW[3], rW[4], rW[5], rW[6], rW[7], rW[8], rW[9]);
    transpose_half<<<dim3(32, 32, B), 256, 0, stream>>>(sh, shT);
    rc_fused<<<dim3(PB, B), 256, 0, stream>>>(
        shT, u, dB, alpha, v,
        cW[0], cW[1], cW[2], cW[3], cW[4], cW[5], cW[6], cW[7], cW[8], cW[9]);

    for (int it = 1; it < 3; ++it) {
        rc_fused<<<dim3(PB, B), 256, 0, stream>>>(
            sh, v, dA, alpha, u,
            rW[0], rW[1], rW[2], rW[3], rW[4], rW[5], rW[6], rW[7], rW[8], rW[9]);
        rc_fused<<<dim3(PB, B), 256, 0, stream>>>(
            shT, u, dB, alpha, v,
            cW[0], cW[1], cW[2], cW[3], cW[4], cW[5], cW[6], cW[7], cW[8], cW[9]);
    }
    final_kernel<<<dim3(MP1, B), 256, 0, stream>>>(sh, alpha, u, v, out);
}

// Round 8
// 333.092 us; speedup vs baseline: 1.0733x; 1.0108x over previous
//
#include <hip/hip_runtime.h>
#include <hip/hip_fp16.h>
#include <math.h>

#define LOG2E 1.4426950408889634f
#define LN2F  0.6931471805599453f

constexpr int M   = 2048;
constexpr int N   = 2048;
constexpr int D   = 256;
constexpr int K   = 2048;   // reduce length (both directions)
constexpr int MP1 = 2049;   // M+1 == N+1
constexpr int UVS = 2052;   // padded u/v batch stride -> float4-aligned rows

struct alignas(16) half8 { __half2 h[4]; };

__device__ inline half8 pack_half8(const float4& a, const float4& b) {
    half8 r;
    r.h[0] = __floats2half2_rn(a.x, a.y);
    r.h[1] = __floats2half2_rn(a.z, a.w);
    r.h[2] = __floats2half2_rn(b.x, b.y);
    r.h[3] = __floats2half2_rn(b.z, b.w);
    return r;
}

__device__ inline float fast_exp2(float x) {
#if __has_builtin(__builtin_amdgcn_exp2f)
    return __builtin_amdgcn_exp2f(x);
#else
    return exp2f(x);
#endif
}
__device__ inline float fast_log2(float x) {
#if __has_builtin(__builtin_amdgcn_logf)
    return __builtin_amdgcn_logf(x);   // v_log_f32 is log2
#else
    return log2f(x);
#endif
}
// NaN-guarded exp2 for identity (-inf) merges
__device__ inline float exp2g(float x) { return fast_exp2(fmaxf(x, -20000.0f)); }

__device__ inline void insert5(float t[5], float y) {
    float v = y, mx;
    #pragma unroll
    for (int k = 0; k < 5; ++k) { mx = fmaxf(t[k], v); v = fminf(t[k], v); t[k] = mx; }
}

__device__ inline void ce_desc(float& a, float& b) {
    float hi = fmaxf(a, b), lo = fminf(a, b); a = hi; b = lo;
}
// 19-CE sorting network for 8 elements, descending (y[0] = max).
__device__ inline void sort8_desc(float y[8]) {
    ce_desc(y[0],y[1]); ce_desc(y[2],y[3]); ce_desc(y[4],y[5]); ce_desc(y[6],y[7]);
    ce_desc(y[0],y[2]); ce_desc(y[1],y[3]); ce_desc(y[4],y[6]); ce_desc(y[5],y[7]);
    ce_desc(y[1],y[2]); ce_desc(y[5],y[6]); ce_desc(y[0],y[4]); ce_desc(y[3],y[7]);
    ce_desc(y[1],y[5]); ce_desc(y[2],y[6]);
    ce_desc(y[1],y[4]); ce_desc(y[3],y[6]);
    ce_desc(y[2],y[4]); ce_desc(y[3],y[5]);
    ce_desc(y[3],y[4]);
}

// top5-only merge: no lse state, no exp2 -- pure min/max network
__device__ inline void merge5t(float a[5], const float b[5]) {
    float r0 = fmaxf(a[0], b[0]);
    float r1 = fmaxf(fmaxf(a[1], b[1]), fminf(a[0], b[0]));
    float r2 = fmaxf(fmaxf(a[2], b[2]), fmaxf(fminf(a[1], b[0]), fminf(a[0], b[1])));
    float r3 = fmaxf(fmaxf(a[3], b[3]),
               fmaxf(fmaxf(fminf(a[2], b[0]), fminf(a[1], b[1])), fminf(a[0], b[2])));
    float r4 = fmaxf(fmaxf(a[4], b[4]),
               fmaxf(fmaxf(fminf(a[3], b[0]), fminf(a[2], b[1])),
                     fmaxf(fminf(a[1], b[2]), fminf(a[0], b[3]))));
    a[0] = r0; a[1] = r1; a[2] = r2; a[3] = r3; a[4] = r4;
}

__device__ inline void merge5t_shfl_xor(float t[5], int off) {
    float b[5];
    #pragma unroll
    for (int k = 0; k < 5; ++k) b[k] = __shfl_xor(t[k], off, 64);
    merge5t(t, b);
}

// dual top5-only butterfly level
__device__ inline void merge5t_shfl_xor2(float tA[5], float tB[5], int off) {
    float bA[5], bB[5];
    #pragma unroll
    for (int k = 0; k < 5; ++k) { bA[k] = __shfl_xor(tA[k], off, 64); bB[k] = __shfl_xor(tB[k], off, 64); }
    merge5t(tA, bA);
    merge5t(tB, bB);
}

__device__ inline void online_add(float t[5], float& s, float y) {
    float m_old = t[0];
    float m_new = fmaxf(m_old, y);
    s = s * exp2g(m_old - m_new) + fast_exp2(y - m_new);
    insert5(t, y);
}

// sort group of 8, record per-group (max, sum-at-max), fold top5 only
__device__ inline void group_accum_t(bool first, float t[5], float z[8],
                                     float& mgv, float& sgv) {
    sort8_desc(z);
    float gs = 1.0f;
    #pragma unroll
    for (int k = 1; k < 8; ++k) gs += fast_exp2(z[k] - z[0]);
    mgv = z[0]; sgv = gs;
    if (first) { t[0]=z[0]; t[1]=z[1]; t[2]=z[2]; t[3]=z[3]; t[4]=z[4]; }
    else merge5t(t, z);
}

__device__ inline float gelu_exact(float x) {
    return 0.5f * x * (1.0f + erff(x * 0.70710678118654752f));
}

__device__ inline float wave_sum(float x) {
    #pragma unroll
    for (int off = 32; off >= 1; off >>= 1) x += __shfl_xor(x, off, 64);
    return x;
}
__device__ inline void wave_sum2(float& x, float& y) {
    #pragma unroll
    for (int off = 32; off >= 1; off >>= 1) {
        float xs = __shfl_xor(x, off, 64);
        float ys = __shfl_xor(y, off, 64);
        x += xs; y += ys;
    }
}
__device__ inline void wave_sum4(float& a, float& b, float& c, float& d) {
    #pragma unroll
    for (int off = 32; off >= 1; off >>= 1) {
        float as = __shfl_xor(a, off, 64);
        float bs = __shfl_xor(b, off, 64);
        float cs = __shfl_xor(c, off, 64);
        float ds = __shfl_xor(d, off, 64);
        a += as; b += bs; c += cs; d += ds;
    }
}

// one-wave MLP, fused-moment LN (single wave_sum2 of (sum, sumsq) per LN).
__device__ inline float mlp_wave_fast(const float f[16], int j,
    const float* __restrict__ w1, const float* __restrict__ b1,
    const float* __restrict__ g1, const float* __restrict__ be1,
    const float* __restrict__ w2, const float* __restrict__ b2,
    const float* __restrict__ g2, const float* __restrict__ be2,
    const float* __restrict__ w3, const float* __restrict__ b3)
{
    float h = b1[j];
    #pragma unroll
    for (int k = 0; k < 16; ++k) h = fmaf(f[k], w1[j * 16 + k], h);
    h = gelu_exact(h);
    float sm = h, sq = h * h;
    wave_sum2(sm, sq);
    float mu  = sm * (1.0f / 64.0f);
    float var = sq * (1.0f / 64.0f) - mu * mu;
    float hn  = (h - mu) * rsqrtf(var + 1e-5f) * g1[j] + be1[j];

    float a0 = b2[j], a1 = 0.0f;
    #pragma unroll
    for (int k = 0; k < 64; k += 2) {
        a0 = fmaf(__shfl(hn, k, 64),     w2[j * 64 + k],     a0);
        a1 = fmaf(__shfl(hn, k + 1, 64), w2[j * 64 + k + 1], a1);
    }
    float h2 = gelu_exact(a0 + a1);
    sm = h2; sq = h2 * h2;
    wave_sum2(sm, sq);
    mu  = sm * (1.0f / 64.0f);
    var = sq * (1.0f / 64.0f) - mu * mu;
    float hn2 = (h2 - mu) * rsqrtf(var + 1e-5f) * g2[j] + be2[j];
    return wave_sum(hn2 * w3[j]) + b3[0];
}

// dual MLP, fused-moment LN via wave_sum4 (both rows' (sum,sumsq) in one butterfly)
__device__ inline void mlp_wave2_fast(const float fA[16], const float fB[16], int j,
    const float* __restrict__ w1, const float* __restrict__ b1,
    const float* __restrict__ g1, const float* __restrict__ be1,
    const float* __restrict__ w2, const float* __restrict__ b2,
    const float* __restrict__ g2, const float* __restrict__ be2,
    const float* __restrict__ w3, const float* __restrict__ b3,
    float& oA, float& oB)
{
    float hA = b1[j], hB = hA;
    #pragma unroll
    for (int k = 0; k < 16; ++k) {
        float w = w1[j * 16 + k];
        hA = fmaf(fA[k], w, hA);
        hB = fmaf(fB[k], w, hB);
    }
    hA = gelu_exact(hA); hB = gelu_exact(hB);
    float smA = hA, sqA = hA * hA, smB = hB, sqB = hB * hB;
    wave_sum4(smA, sqA, smB, sqB);
    float muA = smA * (1.0f / 64.0f), muB = smB * (1.0f / 64.0f);
    float vA  = sqA * (1.0f / 64.0f) - muA * muA;
    float vB  = sqB * (1.0f / 64.0f) - muB * muB;
    float hnA = (hA - muA) * rsqrtf(vA + 1e-5f) * g1[j] + be1[j];
    float hnB = (hB - muB) * rsqrtf(vB + 1e-5f) * g1[j] + be1[j];

    float a0A = b2[j], a1A = 0.0f, a0B = b2[j], a1B = 0.0f;
    #pragma unroll
    for (int k = 0; k < 64; k += 2) {
        float w0 = w2[j * 64 + k], w1v = w2[j * 64 + k + 1];
        float sA0 = __shfl(hnA, k, 64),     sB0 = __shfl(hnB, k, 64);
        float sA1 = __shfl(hnA, k + 1, 64), sB1 = __shfl(hnB, k + 1, 64);
        a0A = fmaf(sA0, w0, a0A); a0B = fmaf(sB0, w0, a0B);
        a1A = fmaf(sA1, w1v, a1A); a1B = fmaf(sB1, w1v, a1B);
    }
    float h2A = gelu_exact(a0A + a1A), h2B = gelu_exact(a0B + a1B);
    smA = h2A; sqA = h2A * h2A; smB = h2B; sqB = h2B * h2B;
    wave_sum4(smA, sqA, smB, sqB);
    muA = smA * (1.0f / 64.0f); muB = smB * (1.0f / 64.0f);
    vA  = sqA * (1.0f / 64.0f) - muA * muA;
    vB  = sqB * (1.0f / 64.0f) - muB * muB;
    float hn2A = (h2A - muA) * rsqrtf(vA + 1e-5f) * g2[j] + be2[j];
    float hn2B = (h2B - muB) * rsqrtf(vB + 1e-5f) * g2[j] + be2[j];
    float zA = hn2A * w3[j], zB = hn2B * w3[j];
    wave_sum2(zA, zB);
    oA = zA + b3[0];
    oB = zB + b3[0];
}

__device__ inline void feats_from(const float t[5], float s, float l2w,
                                  const float* __restrict__ dd, float f[16], float& un)
{
    float lse = t[0] + fast_log2(s);
    un = l2w - lse;
    f[0] = l2w * LN2F;
    f[1] = un  * LN2F;
    f[2] = 0.0f;
    f[3] = (t[0] - t[1]) * LN2F;
    f[4] = (t[0] - t[2]) * LN2F;
    f[5] = (t[0] - t[3]) * LN2F;
    f[6] = (t[0] - t[4]) * LN2F;
    f[7] = (lse - t[0]) * LN2F;
    #pragma unroll
    for (int p = 0; p < 8; ++p) f[8 + p] = dd[p];
}

// ---------------------------------------------------------------------------
// proj, K-split: grid (9, B, 16) [z = which*8 + ks], block 256. (unchanged)
// ---------------------------------------------------------------------------
__global__ __launch_bounds__(256) void proj_part(
    const float* __restrict__ mdesc0, const float* __restrict__ mdesc1,
    const float* __restrict__ pA_w, const float* __restrict__ pB_w,
    float* __restrict__ ppart, int B)
{
    const int which = blockIdx.z >> 3;
    const int ks    = blockIdx.z & 7;
    const float* mdesc = which ? mdesc1 : mdesc0;
    const float* pw    = which ? pB_w : pA_w;

    __shared__ float swT[32 * 8];   // swT[d0*8+p]
    const int tid = threadIdx.x;
    {
        int p = tid >> 5, d0 = tid & 31;
        swT[d0 * 8 + p] = pw[p * D + ks * 32 + d0];
    }
    __syncthreads();

    const int m = blockIdx.x * 256 + tid;
    const int b = blockIdx.y;
    if (m >= M) return;

    float acc[8];
    #pragma unroll
    for (int p = 0; p < 8; ++p) acc[p] = 0.0f;
    const float* base = mdesc + ((size_t)b * D + ks * 32) * M + m;
    #pragma unroll 4
    for (int d0 = 0; d0 < 32; ++d0) {
        float x = base[(size_t)d0 * M];
        #pragma unroll
        for (int p = 0; p < 8; ++p) acc[p] = fmaf(x, swT[d0 * 8 + p], acc[p]);
    }
    float4* o = (float4*)(ppart + (((size_t)(which * B + b)) * MP1 + m) * 64 + ks * 8);
    o[0] = make_float4(acc[0], acc[1], acc[2], acc[3]);
    o[1] = make_float4(acc[4], acc[5], acc[6], acc[7]);
}

// grid (9, B, 2), block 256: sum 8 K-partials + bias; dustbin row m==M -> 0
__global__ __launch_bounds__(256) void proj_combine(
    const float* __restrict__ ppart,
    const float* __restrict__ pA_b, const float* __restrict__ pB_b,
    float* __restrict__ dA, float* __restrict__ dB, int B)
{
    const int which = blockIdx.z;
    const float* pb = which ? pB_b : pA_b;
    float* dOut     = which ? dB   : dA;
    const int m = blockIdx.x * 256 + threadIdx.x;
    const int b = blockIdx.y;
    if (m > M) return;
    float* out = dOut + ((size_t)b * MP1 + m) * 8;
    if (m == M) {
        #pragma unroll
        for (int p = 0; p < 8; ++p) out[p] = 0.0f;
        return;
    }
    float acc[8];
    #pragma unroll
    for (int p = 0; p < 8; ++p) acc[p] = pb[p];
    const float4* pp = (const float4*)(ppart + (((size_t)(which * B + b)) * MP1 + m) * 64);
    #pragma unroll
    for (int ks = 0; ks < 8; ++ks) {
        float4 x0 = pp[2 * ks], x1 = pp[2 * ks + 1];
        acc[0] += x0.x; acc[1] += x0.y; acc[2] += x0.z; acc[3] += x0.w;
        acc[4] += x1.x; acc[5] += x1.y; acc[6] += x1.z; acc[7] += x1.w;
    }
    #pragma unroll
    for (int p = 0; p < 8; ++p) out[p] = acc[p];
}

// ---------------------------------------------------------------------------
// Iter-0 row pass: reads fp32 scores (v==0), writes fp16 copy sh, fused MLP.
// grid (1025, B), block 64 = ONE wave, TWO rows per wave. Single-wave
// workgroups fill all VGPR-permitted wave slots (no 4-wave convoy).
// ---------------------------------------------------------------------------
__global__ __launch_bounds__(64) void row0_fused(
    const float* __restrict__ scores, __half* __restrict__ sh,
    const float* __restrict__ alpha, const float* __restrict__ dA,
    float* __restrict__ u,
    const float* __restrict__ w1, const float* __restrict__ b1,
    const float* __restrict__ g1, const float* __restrict__ be1,
    const float* __restrict__ w2, const float* __restrict__ b2,
    const float* __restrict__ g2, const float* __restrict__ be2,
    const float* __restrict__ w3, const float* __restrict__ b3)
{
    const int lane = threadIdx.x;
    const int r0   = blockIdx.x * 2;
    if (r0 >= MP1) return;
    const int b = blockIdx.y;
    const float alpha2 = alpha[0] * LOG2E;

    if (r0 < M) {
        const float4* sA4 = (const float4*)(scores + ((size_t)b * M + r0) * N);
        const float4* sB4 = sA4 + (N / 4);
        half8* hA8 = (half8*)(sh + ((size_t)b * M + r0) * N);
        half8* hB8 = hA8 + (N / 8);
        float tA[5], tB[5];
        float mgA[4], sgA[4], mgB[4], sgB[4];
        #pragma unroll
        for (int j = 0; j < 4; ++j) {
            float4 qa0 = sA4[2 * lane + 128 * j], qa1 = sA4[2 * lane + 128 * j + 1];
            float4 qb0 = sB4[2 * lane + 128 * j], qb1 = sB4[2 * lane + 128 * j + 1];
            hA8[64 * j + lane] = pack_half8(qa0, qa1);
            hB8[64 * j + lane] = pack_half8(qb0, qb1);
            float zA[8] = {qa0.x*LOG2E, qa0.y*LOG2E, qa0.z*LOG2E, qa0.w*LOG2E,
                           qa1.x*LOG2E, qa1.y*LOG2E, qa1.z*LOG2E, qa1.w*LOG2E};
            float zB[8] = {qb0.x*LOG2E, qb0.y*LOG2E, qb0.z*LOG2E, qb0.w*LOG2E,
                           qb1.x*LOG2E, qb1.y*LOG2E, qb1.z*LOG2E, qb1.w*LOG2E};
            group_accum_t(j == 0, tA, zA, mgA[j], sgA[j]);
            group_accum_t(j == 0, tB, zB, mgB[j], sgB[j]);
        }

        // top5-only dual butterfly (no exp2, no s in the chain)
        #pragma unroll
        for (int off = 32; off >= 1; off >>= 1) merge5t_shfl_xor2(tA, tB, off);

        // lse reconstruction: per-lane rescaled group sums, one dual wave-sum
        float mA = tA[0], mB = tB[0];
        float slA = 0.0f, slB = 0.0f;
        #pragma unroll
        for (int j = 0; j < 4; ++j) {
            slA = fmaf(sgA[j], exp2g(mgA[j] - mA), slA);
            slB = fmaf(sgB[j], exp2g(mgB[j] - mB), slB);
        }
        wave_sum2(slA, slB);
        float sA = slA, sB = slB;

        online_add(tA, sA, alpha2);
        online_add(tB, sB, alpha2);

        float fA[16], fB[16], unA, unB;
        const float* ddA = dA + (size_t)(b * MP1 + r0) * 8;
        feats_from(tA, sA, -12.0f, ddA, fA, unA);
        feats_from(tB, sB, -12.0f, ddA + 8, fB, unB);

        float oA, oB;
        mlp_wave2_fast(fA, fB, lane, w1, b1, g1, be1, w2, b2, g2, be2, w3, b3, oA, oB);
        if (lane == 0) {
            u[(size_t)b * UVS + r0]     = unA + oA * LOG2E;
            u[(size_t)b * UVS + r0 + 1] = unB + oB * LOG2E;
        }
    } else {
        // dustbin row r0 == M: all elements alpha2
        float t[5] = {alpha2, alpha2, alpha2, alpha2, alpha2};
        float s = 2049.0f;
        float f[16], un;
        const float* dd = dA + (size_t)(b * MP1 + M) * 8;
        feats_from(t, s, -1.0f, dd, f, un);
        float o = mlp_wave_fast(f, lane, w1, b1, g1, be1, w2, b2, g2, be2, w3, b3);
        if (lane == 0) u[(size_t)b * UVS + M] = un + o * LOG2E;
    }
}

// ---------------------------------------------------------------------------
// fp16 transpose: sh[b][r][c] -> shT[b][c][r]. 64x64 LDS tiles. (unchanged)
// ---------------------------------------------------------------------------
__global__ __launch_bounds__(256) void transpose_half(
    const __half* __restrict__ sh, __half* __restrict__ shT)
{
    __shared__ unsigned short a[64][65];
    const int b  = blockIdx.z;
    const int r0 = blockIdx.x * 64;
    const int c0 = blockIdx.y * 64;
    const int t  = threadIdx.x;

    const __half* src = sh + ((size_t)b * M + r0) * N + c0;
    #pragma unroll
    for (int i = 0; i < 2; ++i) {
        int s = t + 256 * i;            // 512 half8 slots
        int r = s >> 3, c8 = (s & 7) * 8;
        half8 hv = *(const half8*)(src + (size_t)r * N + c8);
        const unsigned short* pv = (const unsigned short*)&hv;
        #pragma unroll
        for (int k = 0; k < 8; ++k) a[r][c8 + k] = pv[k];
    }
    __syncthreads();
    __half* dst = shT + ((size_t)b * N + c0) * M + r0;
    #pragma unroll
    for (int i = 0; i < 2; ++i) {
        int s = t + 256 * i;
        int c = s >> 3, r8 = (s & 7) * 8;
        half8 ov;
        unsigned short* po = (unsigned short*)&ov;
        #pragma unroll
        for (int k = 0; k < 8; ++k) po[k] = a[r8 + k][c];
        *(half8*)(dst + (size_t)c * M + r8) = ov;
    }
}

// ---------------------------------------------------------------------------
// Generic fp16 reduce + fused MLP pass (rows or cols).
// grid (1025, B), block 64 = ONE wave, TWO outputs per wave. Direct vk
// loads, no LDS, no barrier. Split-lse butterfly + fused-moment LN MLP.
// ---------------------------------------------------------------------------
__global__ __launch_bounds__(64) void rc_fused(
    const __half* __restrict__ mat, const float* __restrict__ vk_base,
    const float* __restrict__ desc, const float* __restrict__ alpha,
    float* __restrict__ out,
    const float* __restrict__ w1, const float* __restrict__ b1,
    const float* __restrict__ g1, const float* __restrict__ be1,
    const float* __restrict__ w2, const float* __restrict__ b2,
    const float* __restrict__ g2, const float* __restrict__ be2,
    const float* __restrict__ w3, const float* __restrict__ b3)
{
    const int lane = threadIdx.x;
    const int i0   = blockIdx.x * 2;
    if (i0 >= MP1) return;
    const int b = blockIdx.y;
    const float alpha2 = alpha[0] * LOG2E;
    const float* vk = vk_base + (size_t)b * UVS;
    const float4* vk4 = (const float4*)vk;

    if (i0 < M) {
        const half8* hA8 = (const half8*)(mat + ((size_t)b * M + i0) * K);
        const half8* hB8 = hA8 + (K / 8);
        half8 ha[4], hb[4];
        float4 vv[8];
        #pragma unroll
        for (int j = 0; j < 4; ++j) { ha[j] = hA8[64 * j + lane]; hb[j] = hB8[64 * j + lane]; }
        #pragma unroll
        for (int j = 0; j < 4; ++j) {
            vv[2 * j]     = vk4[2 * lane + 128 * j];
            vv[2 * j + 1] = vk4[2 * lane + 128 * j + 1];
        }
        float tA[5], tB[5];
        float mgA[4], sgA[4], mgB[4], sgB[4];
        #pragma unroll
        for (int j = 0; j < 4; ++j) {
            float2 a0 = __half22float2(ha[j].h[0]), a1 = __half22float2(ha[j].h[1]);
            float2 a2 = __half22float2(ha[j].h[2]), a3 = __half22float2(ha[j].h[3]);
            float2 b0 = __half22float2(hb[j].h[0]), b1v = __half22float2(hb[j].h[1]);
            float2 b2v = __half22float2(hb[j].h[2]), b3v = __half22float2(hb[j].h[3]);
            float4 w0 = vv[2 * j], w1v = vv[2 * j + 1];
            float zA[8] = {fmaf(a0.x,LOG2E,w0.x),  fmaf(a0.y,LOG2E,w0.y),
                           fmaf(a1.x,LOG2E,w0.z),  fmaf(a1.y,LOG2E,w0.w),
                           fmaf(a2.x,LOG2E,w1v.x), fmaf(a2.y,LOG2E,w1v.y),
                           fmaf(a3.x,LOG2E,w1v.z), fmaf(a3.y,LOG2E,w1v.w)};
            float zB[8] = {fmaf(b0.x,LOG2E,w0.x),  fmaf(b0.y,LOG2E,w0.y),
                           fmaf(b1v.x,LOG2E,w0.z), fmaf(b1v.y,LOG2E,w0.w),
                           fmaf(b2v.x,LOG2E,w1v.x), fmaf(b2v.y,LOG2E,w1v.y),
                           fmaf(b3v.x,LOG2E,w1v.z), fmaf(b3v.y,LOG2E,w1v.w)};
            group_accum_t(j == 0, tA, zA, mgA[j], sgA[j]);
            group_accum_t(j == 0, tB, zB, mgB[j], sgB[j]);
        }

        // top5-only dual butterfly
        #pragma unroll
        for (int off = 32; off >= 1; off >>= 1) merge5t_shfl_xor2(tA, tB, off);

        // lse reconstruction
        float mA = tA[0], mB = tB[0];
        float slA = 0.0f, slB = 0.0f;
        #pragma unroll
        for (int j = 0; j < 4; ++j) {
            slA = fmaf(sgA[j], exp2g(mgA[j] - mA), slA);
            slB = fmaf(sgB[j], exp2g(mgB[j] - mB), slB);
        }
        wave_sum2(slA, slB);
        float sA = slA, sB = slB;

        float extra = alpha2 + vk[K];
        online_add(tA, sA, extra);
        online_add(tB, sB, extra);

        float fA[16], fB[16], unA, unB;
        const float* ddA = desc + (size_t)(b * MP1 + i0) * 8;
        feats_from(tA, sA, -12.0f, ddA, fA, unA);
        feats_from(tB, sB, -12.0f, ddA + 8, fB, unB);

        float oA, oB;
        mlp_wave2_fast(fA, fB, lane, w1, b1, g1, be1, w2, b2, g2, be2, w3, b3, oA, oB);
        if (lane == 0) {
            out[(size_t)b * UVS + i0]     = unA + oA * LOG2E;
            out[(size_t)b * UVS + i0 + 1] = unB + oB * LOG2E;
        }
    } else {
        // dustbin output i0 == M: z[k] = alpha2 + vk[k]
        float t[5];
        float mg[4], sg[4];
        #pragma unroll
        for (int g = 0; g < 4; ++g) {
            float4 wa = vk4[lane + 128 * g];
            float4 wb = vk4[lane + 128 * g + 64];
            float z[8] = {alpha2+wa.x, alpha2+wa.y, alpha2+wa.z, alpha2+wa.w,
                          alpha2+wb.x, alpha2+wb.y, alpha2+wb.z, alpha2+wb.w};
            group_accum_t(g == 0, t, z, mg[g], sg[g]);
        }
        #pragma unroll
        for (int off = 32; off >= 1; off >>= 1) merge5t_shfl_xor(t, off);
        float m = t[0];
        float sl = 0.0f;
        #pragma unroll
        for (int g = 0; g < 4; ++g) sl = fmaf(sg[g], exp2g(mg[g] - m), sl);
        float s = wave_sum(sl);
        online_add(t, s, alpha2 + vk[K]);

        float f[16], un;
        const float* dd = desc + (size_t)(b * MP1 + M) * 8;
        feats_from(t, s, -1.0f, dd, f, un);
        float o = mlp_wave_fast(f, lane, w1, b1, g1, be1, w2, b2, g2, be2, w3, b3);
        if (lane == 0) out[(size_t)b * UVS + M] = un + o * LOG2E;
    }
}

// ---------------------------------------------------------------------------
// out[b,r,c] = S*LOG2E + u[b,r] + v[b,c] + 12.  grid (2049, B), block 256.
// (unchanged)
// ---------------------------------------------------------------------------
__global__ __launch_bounds__(256) void final_kernel(
    const __half* __restrict__ sh, const float* __restrict__ alpha,
    const float* __restrict__ u, const float* __restrict__ v,
    float* __restrict__ out)
{
    const int r = blockIdx.x;
    const int b = blockIdx.y;
    const int tid = threadIdx.x;
    const float alpha2 = alpha[0] * LOG2E;
    const float* vb = v + (size_t)b * UVS;
    const float4* v4 = (const float4*)vb;
    const float ur = u[(size_t)b * UVS + r] + 12.0f;
    float* orow = out + ((size_t)b * MP1 + r) * MP1;

    float4 w0 = v4[2 * tid], w1v = v4[2 * tid + 1];
    const int c = tid * 8;
    if (r < M) {
        half8 hv = *(const half8*)(sh + ((size_t)b * M + r) * N + c);
        float2 a0 = __half22float2(hv.h[0]), a1 = __half22float2(hv.h[1]);
        float2 a2 = __half22float2(hv.h[2]), a3 = __half22float2(hv.h[3]);
        orow[c]     = fmaf(a0.x, LOG2E, ur + w0.x);
        orow[c + 1] = fmaf(a0.y, LOG2E, ur + w0.y);
        orow[c + 2] = fmaf(a1.x, LOG2E, ur + w0.z);
        orow[c + 3] = fmaf(a1.y, LOG2E, ur + w0.w);
        orow[c + 4] = fmaf(a2.x, LOG2E, ur + w1v.x);
        orow[c + 5] = fmaf(a2.y, LOG2E, ur + w1v.y);
        orow[c + 6] = fmaf(a3.x, LOG2E, ur + w1v.z);
        orow[c + 7] = fmaf(a3.y, LOG2E, ur + w1v.w);
    } else {
        orow[c]     = alpha2 + ur + w0.x;
        orow[c + 1] = alpha2 + ur + w0.y;
        orow[c + 2] = alpha2 + ur + w0.z;
        orow[c + 3] = alpha2 + ur + w0.w;
        orow[c + 4] = alpha2 + ur + w1v.x;
        orow[c + 5] = alpha2 + ur + w1v.y;
        orow[c + 6] = alpha2 + ur + w1v.z;
        orow[c + 7] = alpha2 + ur + w1v.w;
    }
    if (tid == 0) orow[N] = alpha2 + ur + vb[N];
}

extern "C" void kernel_launch(void* const* d_in, const int* in_sizes, int n_in,
                              void* d_out, int out_size, void* d_ws, size_t ws_size,
                              hipStream_t stream) {
    const float* scores = (const float*)d_in[0];
    const float* alpha  = (const float*)d_in[1];
    const float* mdesc0 = (const float*)d_in[2];
    const float* mdesc1 = (const float*)d_in[3];
    const float* pA_w = (const float*)d_in[4];
    const float* pA_b = (const float*)d_in[5];
    const float* pB_w = (const float*)d_in[6];
    const float* pB_b = (const float*)d_in[7];
    const float* rW[10]; const float* cW[10];
    for (int k = 0; k < 10; ++k) rW[k] = (const float*)d_in[8 + k];
    for (int k = 0; k < 10; ++k) cW[k] = (const float*)d_in[18 + k];
    float* out = (float*)d_out;

    const int B = in_sizes[0] / (M * N);

    float* ws = (float*)d_ws;
    float* u     = ws;                              // B*UVS
    float* v     = u + (size_t)B * UVS;             // B*UVS
    float* dA    = v + (size_t)B * UVS;             // B*MP1*8
    float* dB    = dA + (size_t)B * MP1 * 8;        // B*MP1*8
    float* ppart = dB + (size_t)B * MP1 * 8;        // 2*B*MP1*64
    __half* sh   = (__half*)(ppart + (size_t)2 * B * MP1 * 64); // B*M*N halfs
    __half* shT  = sh + (size_t)B * M * N;                      // B*N*M halfs

    const int CB = (MP1 + 255) / 256;           // 9
    const int WB = (MP1 + 1) / 2;               // 1025: one wave (block) per 2 outputs

    proj_part<<<dim3(CB, B, 16), 256, 0, stream>>>(
        mdesc0, mdesc1, pA_w, pB_w, ppart, B);
    proj_combine<<<dim3(CB, B, 2), 256, 0, stream>>>(
        ppart, pA_b, pB_b, dA, dB, B);

    // iter 0: row pass on fp32 (v == 0), produce sh; transpose; col pass
    row0_fused<<<dim3(WB, B), 64, 0, stream>>>(
        scores, sh, alpha, dA, u,
        rW[0], rW[1], rW[2], rW[3], rW[4], rW[5], rW[6], rW[7], rW[8], rW[9]);
    transpose_half<<<dim3(32, 32, B), 256, 0, stream>>>(sh, shT);
    rc_fused<<<dim3(WB, B), 64, 0, stream>>>(
        shT, u, dB, alpha, v,
        cW[0], cW[1], cW[2], cW[3], cW[4], cW[5], cW[6], cW[7], cW[8], cW[9]);

    for (int it = 1; it < 3; ++it) {
        rc_fused<<<dim3(WB, B), 64, 0, stream>>>(
            sh, v, dA, alpha, u,
            rW[0], rW[1], rW[2], rW[3], rW[4], rW[5], rW[6], rW[7], rW[8], rW[9]);
        rc_fused<<<dim3(WB, B), 64, 0, stream>>>(
            shT, u, dB, alpha, v,
            cW[0], cW[1], cW[2], cW[3], cW[4], cW[5], cW[6], cW[7], cW[8], cW[9]);
    }
    final_kernel<<<dim3(MP1, B), 256, 0, stream>>>(sh, alpha, u, v, out);
}